// Round 1
// baseline (274.469 us; speedup 1.0000x reference)
//
#include <hip/hip_runtime.h>
#include <hip/hip_bf16.h>

#define DEV static __device__ __forceinline__

constexpr int B=16, N=128, FIN=128, FOUT=256, EOUT=64, BINW=14, BOUT=64, CI=64, L1=256;

// ---- workspace layout (float offsets) ----
constexpr int HDR=16;
constexpr int O_X    = HDR;
constexpr int O_WE   = O_X + B*N*FIN;
constexpr int O_W    = O_WE + B*N*N*BINW;
constexpr int O_A    = O_W + FIN*FOUT;
constexpr int O_WFCW = O_A + 2*FOUT*EOUT;
constexpr int O_WFCB = O_WFCW + BINW*BOUT;
constexpr int O_FCW  = O_WFCB + BOUT;
constexpr int O_FCB  = O_FCW + (EOUT+BOUT);
constexpr int O_FCCW = O_FCB + 1;
constexpr int O_FCCB = O_FCCW + FOUT;
constexpr int O_WIHF = O_FCCB + 1;
constexpr int O_WHHF = O_WIHF + CI*N;
constexpr int O_BIHF = O_WHHF + CI*CI;
constexpr int O_BHHF = O_BIHF + CI;
constexpr int O_WIHB = O_BHHF + CI;
constexpr int O_WHHB = O_WIHB + CI*N;
constexpr int O_BIHB = O_WHHB + CI*CI;
constexpr int O_BHHB = O_BIHB + CI;
constexpr int O_FCOW = O_BHHB + CI;
constexpr int O_FCOB = O_FCOW + (2*CI+FOUT)*L1;
constexpr int CONV_END = O_FCOB + L1;
constexpr int CONV_TOTAL = CONV_END - HDR;
constexpr int O_SCR = ((CONV_END+127)/128)*128;
constexpr int O_H  = O_SCR;               // [B,N,FOUT]
constexpr int O_P  = O_H + B*N*FOUT;      // [B,N,EOUT]
constexpr int O_Q  = O_P + B*N*EOUT;
constexpr int O_S  = O_Q + B*N*EOUT;      // [B,N]
constexpr int O_SU = O_S + B*N;
constexpr int O_SV = O_SU + B*N;
constexpr int O_ZF = O_SV + B*N;          // [B,N,CI]
constexpr int O_ZB = O_ZF + B*N*CI;
constexpr int O_RF = O_ZB + B*N*CI;
constexpr int O_RB = O_RF + B*N*CI;
constexpr int O_H1 = O_RB + B*N*CI;       // [B,N,FOUT]

constexpr int NCONV=20;
__constant__ int CCUM[NCONV+1] = {
  0,
  O_WE-HDR, O_W-HDR, O_A-HDR, O_WFCW-HDR, O_WFCB-HDR, O_FCW-HDR, O_FCB-HDR,
  O_FCCW-HDR, O_FCCB-HDR, O_WIHF-HDR, O_WHHF-HDR, O_BIHF-HDR, O_BHHF-HDR,
  O_WIHB-HDR, O_WHHB-HDR, O_BIHB-HDR, O_BHHB-HDR, O_FCOW-HDR, O_FCOB-HDR,
  CONV_TOTAL
};

DEV float bf16_to_f32(unsigned short u){
  unsigned int x = ((unsigned int)u) << 16; float f;
  __builtin_memcpy(&f, &x, 4); return f;
}
DEV float lrelu(float x){ return x > 0.f ? x : 0.01f * x; }

// detect whether the float tensors were delivered as bf16 (vs f32).
// If f32: even-indexed 16-bit halves are low mantissa bits -> random exponents.
DEV int detect_bf16(const void* x){
  const unsigned short* u = (const unsigned short*)x;
  int cnt = 0;
  for (int k = 0; k < 128; ++k){
    int e = (u[k] >> 7) & 0xFF;
    if (e >= 100 && e <= 140) cnt++;
  }
  return cnt >= 110;
}

struct ConvArgs { const void* p[NCONV]; };

// K0: convert every float input to f32, contiguous in ws
__global__ __launch_bounds__(256) void k_convert(ConvArgs a, float* ws){
  __shared__ int smode;
  if (threadIdx.x == 0) smode = detect_bf16(a.p[0]);
  __syncthreads();
  int mode = smode;
  for (int gid = blockIdx.x*256 + threadIdx.x; gid < CONV_TOTAL; gid += gridDim.x*256){
    int t = 0;
    while (gid >= CCUM[t+1]) t++;
    int local = gid - CCUM[t];
    float v = mode ? bf16_to_f32(((const unsigned short*)a.p[t])[local])
                   : ((const float*)a.p[t])[local];
    ws[HDR + gid] = v;
  }
}

// K1: h = x@W ; s = h·fcc_w ; P = h@a_top ; Q = h@a_bot   (4 rows per block)
__global__ __launch_bounds__(256) void k_h_pq(float* ws){
  int blk = blockIdx.x, tid = threadIdx.x;
  int b = blk >> 5, i0 = (blk & 31) * 4;
  __shared__ float xl[4*FIN];
  __shared__ float hrow[4*FOUT];
  __shared__ float red[16];
  for (int t = tid; t < 4*FIN; t += 256) xl[t] = ws[O_X + (b*N + i0)*FIN + t];
  __syncthreads();
  float acc[4] = {0.f,0.f,0.f,0.f};
  int f = tid;
  for (int c = 0; c < FIN; ++c){
    float w = ws[O_W + c*FOUT + f];
    #pragma unroll
    for (int r = 0; r < 4; ++r) acc[r] += xl[r*FIN + c] * w;
  }
  float fw = ws[O_FCCW + f];
  #pragma unroll
  for (int r = 0; r < 4; ++r){
    ws[O_H + (b*N + i0 + r)*FOUT + f] = acc[r];
    hrow[r*FOUT + f] = acc[r];
  }
  #pragma unroll
  for (int r = 0; r < 4; ++r){
    float v = acc[r] * fw;
    for (int off = 32; off; off >>= 1) v += __shfl_down(v, off);
    if ((tid & 63) == 0) red[(tid >> 6)*4 + r] = v;
  }
  __syncthreads();
  if (tid < 4){
    float s = red[0*4+tid] + red[1*4+tid] + red[2*4+tid] + red[3*4+tid];
    ws[O_S + b*N + i0 + tid] = s;
  }
  // P/Q
  if (tid < 128){
    int o = tid & 63, which = tid >> 6;
    float a4[4] = {0.f,0.f,0.f,0.f};
    for (int c = 0; c < FOUT; ++c){
      float w = ws[O_A + (which*FOUT + c)*EOUT + o];
      #pragma unroll
      for (int r = 0; r < 4; ++r) a4[r] += hrow[r*FOUT + c] * w;
    }
    int ob = which ? O_Q : O_P;
    #pragma unroll
    for (int r = 0; r < 4; ++r) ws[ob + (b*N + i0 + r)*EOUT + o] = a4[r];
  }
}

// K2: su[b,r] = sum_o lrelu(P+Q)*fcw[o] ; sv[b,r] from rows (2r)%128,(2r)%128+1
__global__ __launch_bounds__(64) void k_susv(float* ws){
  int blk = blockIdx.x; int b = blk >> 7, r = blk & 127; int o = threadIdx.x;
  float fw = ws[O_FCW + o];
  float u = ws[O_P + (b*N + r)*EOUT + o] + ws[O_Q + (b*N + r)*EOUT + o];
  float t1 = lrelu(u) * fw;
  int j2 = (2*r) & 127;
  float v = ws[O_P + (b*N + j2)*EOUT + o] + ws[O_Q + (b*N + j2 + 1)*EOUT + o];
  float t2 = lrelu(v) * fw;
  for (int off = 32; off; off >>= 1){ t1 += __shfl_down(t1, off); t2 += __shfl_down(t2, off); }
  if (o == 0){ ws[O_SU + b*N + r] = t1; ws[O_SV + b*N + r] = t2; }
}

// K3: per (b,i) row: edge-MLP scalar + mask + softmax -> att ; hn_pre ; z (RNN input GEMM) ; h1 = att@h
__global__ __launch_bounds__(128) void k_att(const int* __restrict__ adj, float* ws){
  int blk = blockIdx.x; int b = blk >> 7, i = blk & 127; int tid = threadIdx.x;
  __shared__ float wel[N*BINW];
  __shared__ float wfcwl[BINW*BOUT];
  __shared__ float fcw2l[BOUT];
  __shared__ float attl[N];
  __shared__ float hnp[N];
  __shared__ float red2[2];
  int base_we = (b*N + i)*N*BINW;
  for (int t = tid; t < N*BINW; t += 128) wel[t] = ws[O_WE + base_we + t];
  for (int t = tid; t < BINW*BOUT; t += 128) wfcwl[t] = ws[O_WFCW + t];
  if (tid < BOUT) fcw2l[tid] = ws[O_FCW + EOUT + tid];
  __syncthreads();
  int j = tid;
  float wr[BINW];
  #pragma unroll
  for (int t = 0; t < BINW; ++t) wr[t] = wel[j*BINW + t];
  float wcon = 0.f;
  for (int o = 0; o < BOUT; ++o){
    float wp = ws[O_WFCB + o];
    #pragma unroll
    for (int t = 0; t < BINW; ++t) wp += wr[t] * wfcwl[t*BOUT + o];
    wcon += lrelu(wp) * fcw2l[o];
  }
  float econ = (i < 64) ? ws[O_SU + b*N + 2*i + (j >= 64 ? 1 : 0)]
                        : ws[O_SV + b*N + j];
  float etot = econ + wcon + ws[O_FCB];
  float m = (adj[(b*N + i)*N + j] > 0) ? etot : -9e15f;
  // softmax over 128 threads (2 waves)
  float mx = m;
  for (int off = 32; off; off >>= 1) mx = fmaxf(mx, __shfl_xor(mx, off));
  if ((tid & 63) == 0) red2[tid >> 6] = mx;
  __syncthreads();
  mx = fmaxf(red2[0], red2[1]);
  float ev = expf(m - mx);
  float sum = ev;
  for (int off = 32; off; off >>= 1) sum += __shfl_xor(sum, off);
  __syncthreads();               // protect red2 reuse
  if ((tid & 63) == 0) red2[tid >> 6] = sum;
  __syncthreads();
  sum = red2[0] + red2[1];
  float att = ev / sum;
  attl[j] = att;
  float sbi = ws[O_S + b*N + i];
  hnp[j] = lrelu(att * sbi + ws[O_FCCB]);
  __syncthreads();
  // z[b,i,c] for both directions: z = hnp·wih[c,:] + bih[c] + bhh[c]
  {
    int d = tid >> 6, c = tid & 63;
    int wb = d ? O_WIHB : O_WIHF;
    float acc = ws[(d ? O_BIHB : O_BIHF) + c] + ws[(d ? O_BHHB : O_BHHF) + c];
    for (int k = 0; k < N; ++k) acc += hnp[k] * ws[wb + c*N + k];
    ws[(d ? O_ZB : O_ZF) + (b*N + i)*CI + c] = acc;
  }
  // h1[b,i,f] = sum_j att[j] * h[b,j,f]
  for (int f = tid; f < FOUT; f += 128){
    float acc = 0.f;
    for (int k = 0; k < N; ++k) acc += attl[k] * ws[O_H + (b*N + k)*FOUT + f];
    ws[O_H1 + (b*N + i)*FOUT + f] = acc;
  }
}

// K4: recurrent part. one block per (direction, batch), 64 threads = hidden dim
__global__ __launch_bounds__(64) void k_rnn(float* ws){
  int blk = blockIdx.x; int d = blk >> 4, b = blk & 15; int c = threadIdx.x;
  __shared__ float hl[CI];
  float wreg[CI];
  int wb = d ? O_WHHB : O_WHHF;
  #pragma unroll
  for (int k = 0; k < CI; ++k) wreg[k] = ws[wb + c*CI + k];
  int zb = d ? O_ZB : O_ZF;
  int ob = d ? O_RB : O_RF;
  hl[c] = 0.f;
  __syncthreads();
  for (int t = 0; t < N; ++t){
    int tt = d ? (N - 1 - t) : t;
    float acc = ws[zb + (b*N + tt)*CI + c];
    #pragma unroll
    for (int k = 0; k < CI; ++k) acc += hl[k] * wreg[k];
    float hv = tanhf(acc);
    __syncthreads();
    hl[c] = hv;
    __syncthreads();
    ws[ob + (b*N + tt)*CI + c] = hv;
  }
}

// K5: out = elu(cat(lrelu(rnn), h1) @ fco_w + fco_b)   (4 rows per block)
__global__ __launch_bounds__(256) void k_out(const void* __restrict__ x0, float* ws, void* dout){
  int blk = blockIdx.x, tid = threadIdx.x;
  int b = blk >> 5, i0 = (blk & 31) * 4;
  __shared__ float inl[4*(2*CI + FOUT)];
  __shared__ int smode;
  if (tid == 0) smode = detect_bf16(x0);
  for (int t = tid; t < 4*(2*CI + FOUT); t += 256){
    int r = t / (2*CI + FOUT), k = t % (2*CI + FOUT);
    int row = b*N + i0 + r;
    float v;
    if (k < CI)        v = lrelu(ws[O_RF + row*CI + k]);
    else if (k < 2*CI) v = lrelu(ws[O_RB + row*CI + (k - CI)]);
    else               v = ws[O_H1 + row*FOUT + (k - 2*CI)];
    inl[t] = v;
  }
  __syncthreads();
  int l = tid;
  float acc[4];
  float bias = ws[O_FCOB + l];
  #pragma unroll
  for (int r = 0; r < 4; ++r) acc[r] = bias;
  for (int k = 0; k < 2*CI + FOUT; ++k){
    float w = ws[O_FCOW + k*L1 + l];
    #pragma unroll
    for (int r = 0; r < 4; ++r) acc[r] += inl[r*(2*CI + FOUT) + k] * w;
  }
  int mode = smode;
  #pragma unroll
  for (int r = 0; r < 4; ++r){
    float o = acc[r] > 0.f ? acc[r] : expm1f(acc[r]);
    int idx = (b*N + i0 + r)*L1 + l;
    if (mode) ((__hip_bfloat16*)dout)[idx] = __float2bfloat16(o);
    else      ((float*)dout)[idx] = o;
  }
}

extern "C" void kernel_launch(void* const* d_in, const int* in_sizes, int n_in,
                              void* d_out, int out_size, void* d_ws, size_t ws_size,
                              hipStream_t stream){
  (void)in_sizes; (void)n_in; (void)out_size; (void)ws_size;
  float* ws = (float*)d_ws;
  ConvArgs ca;
  const int map[NCONV] = {0,2,3,4,5,6,7,8,9,10,11,12,13,14,15,16,17,18,19,20};
  for (int t = 0; t < NCONV; ++t) ca.p[t] = d_in[map[t]];
  hipLaunchKernelGGL(k_convert, dim3(2048), dim3(256), 0, stream, ca, ws);
  hipLaunchKernelGGL(k_h_pq,   dim3(B*N/4), dim3(256), 0, stream, ws);
  hipLaunchKernelGGL(k_susv,   dim3(B*N),   dim3(64),  0, stream, ws);
  hipLaunchKernelGGL(k_att,    dim3(B*N),   dim3(128), 0, stream, (const int*)d_in[1], ws);
  hipLaunchKernelGGL(k_rnn,    dim3(32),    dim3(64),  0, stream, ws);
  hipLaunchKernelGGL(k_out,    dim3(B*N/4), dim3(256), 0, stream, d_in[0], ws, d_out);
}

// Round 2
// 267.006 us; speedup vs baseline: 1.0280x; 1.0280x over previous
//
#include <hip/hip_runtime.h>
#include <hip/hip_bf16.h>

#define DEV static __device__ __forceinline__

constexpr int B=16, N=128, FIN=128, FOUT=256, EOUT=64, BINW=14, BOUT=64, CI=64, L1=256;

// ---- workspace layout (float offsets), every region padded to 4-elem (16 B) ----
constexpr int HDR=16;
constexpr int O_X    = HDR;                    // 262144
constexpr int O_WE   = O_X + B*N*FIN;          // 3670016
constexpr int O_W    = O_WE + B*N*N*BINW;      // 32768
constexpr int O_A    = O_W + FIN*FOUT;         // 32768
constexpr int O_WFCW = O_A + 2*FOUT*EOUT;      // 896
constexpr int O_WFCB = O_WFCW + BINW*BOUT;     // 64
constexpr int O_FCW  = O_WFCB + BOUT;          // 128
constexpr int O_FCB  = O_FCW + (EOUT+BOUT);    // 1 -> pad 4
constexpr int O_FCCW = O_FCB + 4;              // 256
constexpr int O_FCCB = O_FCCW + FOUT;          // 1 -> pad 4
constexpr int O_WIHF = O_FCCB + 4;             // 8192
constexpr int O_WHHF = O_WIHF + CI*N;          // 4096
constexpr int O_BIHF = O_WHHF + CI*CI;         // 64
constexpr int O_BHHF = O_BIHF + CI;            // 64
constexpr int O_WIHB = O_BHHF + CI;            // 8192
constexpr int O_WHHB = O_WIHB + CI*N;          // 4096
constexpr int O_BIHB = O_WHHB + CI*CI;         // 64
constexpr int O_BHHB = O_BIHB + CI;            // 64
constexpr int O_FCOW = O_BHHB + CI;            // 106496
constexpr int O_FCOB = O_FCOW + (2*CI+FOUT)*L1;// 256
constexpr int CONV_END = O_FCOB + L1;
constexpr int CONV_TOTAL = CONV_END - HDR;
constexpr int O_SCR = ((CONV_END+127)/128)*128;
constexpr int O_H   = O_SCR;                   // [B,N,FOUT]
constexpr int O_P   = O_H  + B*N*FOUT;         // [B,N,EOUT]
constexpr int O_Q   = O_P  + B*N*EOUT;
constexpr int O_S   = O_Q  + B*N*EOUT;         // [B,N]
constexpr int O_SU  = O_S  + B*N;
constexpr int O_SV  = O_SU + B*N;
constexpr int O_ATT = O_SV + B*N;              // [B,N,N]
constexpr int O_ZF  = O_ATT+ B*N*N;            // [B,N,CI]
constexpr int O_ZB  = O_ZF + B*N*CI;
constexpr int O_RF  = O_ZB + B*N*CI;
constexpr int O_RB  = O_RF + B*N*CI;
constexpr int O_H1  = O_RB + B*N*CI;           // [B,N,FOUT]

constexpr int NCONV=20;
__constant__ int CCUM[NCONV+1] = {
  0,
  O_WE-HDR, O_W-HDR, O_A-HDR, O_WFCW-HDR, O_WFCB-HDR, O_FCW-HDR, O_FCB-HDR,
  O_FCCW-HDR, O_FCCB-HDR, O_WIHF-HDR, O_WHHF-HDR, O_BIHF-HDR, O_BHHF-HDR,
  O_WIHB-HDR, O_WHHB-HDR, O_BIHB-HDR, O_BHHB-HDR, O_FCOW-HDR, O_FCOB-HDR,
  CONV_TOTAL
};
__constant__ int CSIZE[NCONV] = {
  B*N*FIN, B*N*N*BINW, FIN*FOUT, 2*FOUT*EOUT, BINW*BOUT, BOUT, EOUT+BOUT, 1,
  FOUT, 1, CI*N, CI*CI, CI, CI, CI*N, CI*CI, CI, CI, (2*CI+FOUT)*L1, L1
};

DEV float bf16_to_f32(unsigned short u){
  unsigned int x = ((unsigned int)u) << 16; float f;
  __builtin_memcpy(&f, &x, 4); return f;
}
DEV float lrelu(float x){ return x > 0.f ? x : 0.01f * x; }
DEV float bcastf(float v, int lane){
  return __builtin_bit_cast(float, __builtin_amdgcn_readlane(__builtin_bit_cast(int, v), lane));
}

// detect whether the float tensors were delivered as bf16 (vs f32)
DEV int detect_bf16(const void* x){
  const unsigned short* u = (const unsigned short*)x;
  int cnt = 0;
  for (int k = 0; k < 128; ++k){
    int e = (u[k] >> 7) & 0xFF;
    if (e >= 100 && e <= 140) cnt++;
  }
  return cnt >= 110;
}

struct ConvArgs { const void* p[NCONV]; };

// K0: convert every float input to f32, contiguous (padded) in ws
__global__ __launch_bounds__(256) void k_convert(ConvArgs a, float* ws){
  __shared__ int smode;
  if (threadIdx.x == 0) smode = detect_bf16(a.p[0]);
  __syncthreads();
  int mode = smode;
  for (int gid = blockIdx.x*256 + threadIdx.x; gid < CONV_TOTAL; gid += gridDim.x*256){
    int t = 0;
    while (gid >= CCUM[t+1]) t++;
    int local = gid - CCUM[t];
    float v = 0.f;
    if (local < CSIZE[t])
      v = mode ? bf16_to_f32(((const unsigned short*)a.p[t])[local])
               : ((const float*)a.p[t])[local];
    ws[HDR + gid] = v;
  }
}

// K1: h = x@W ; s = h·fcc_w ; P = h@a_top ; Q = h@a_bot   (8 rows per block)
__global__ __launch_bounds__(256) void k_h_pq(const float* __restrict__ R, float* __restrict__ Wr){
  int blk = blockIdx.x, tid = threadIdx.x;
  int b = blk >> 4, i0 = (blk & 15) * 8;
  __shared__ __align__(16) float xl[8*FIN];
  __shared__ __align__(16) float hrow[8*FOUT];
  __shared__ float red[32];
  for (int t4 = tid; t4 < 8*FIN/4; t4 += 256)
    *(float4*)&xl[t4*4] = *(const float4*)&R[O_X + (b*N + i0)*FIN + t4*4];
  __syncthreads();
  int f = tid;
  float acc[8] = {0,0,0,0,0,0,0,0};
  for (int c = 0; c < FIN; c += 4){
    float w0 = R[O_W + (c+0)*FOUT + f];
    float w1 = R[O_W + (c+1)*FOUT + f];
    float w2 = R[O_W + (c+2)*FOUT + f];
    float w3 = R[O_W + (c+3)*FOUT + f];
    #pragma unroll
    for (int r = 0; r < 8; ++r){
      float4 x4 = *(const float4*)&xl[r*FIN + c];
      acc[r] += x4.x*w0 + x4.y*w1 + x4.z*w2 + x4.w*w3;
    }
  }
  float fw = R[O_FCCW + f];
  #pragma unroll
  for (int r = 0; r < 8; ++r){
    Wr[O_H + (b*N + i0 + r)*FOUT + f] = acc[r];
    hrow[r*FOUT + f] = acc[r];
  }
  #pragma unroll
  for (int r = 0; r < 8; ++r){
    float v = acc[r] * fw;
    for (int off = 32; off; off >>= 1) v += __shfl_down(v, off);
    if ((tid & 63) == 0) red[(tid >> 6)*8 + r] = v;
  }
  __syncthreads();
  if (tid < 8){
    float s = red[0*8+tid] + red[1*8+tid] + red[2*8+tid] + red[3*8+tid];
    Wr[O_S + b*N + i0 + tid] = s;
  }
  // P/Q: 4 waves = (which, half-of-rows); per-wave uniform LDS reads (broadcast)
  {
    int o = tid & 63, which = (tid >> 6) & 1, hh = tid >> 7;
    float a4[4] = {0.f,0.f,0.f,0.f};
    for (int c = 0; c < FOUT; c += 4){
      float w0 = R[O_A + (which*FOUT + c+0)*EOUT + o];
      float w1 = R[O_A + (which*FOUT + c+1)*EOUT + o];
      float w2 = R[O_A + (which*FOUT + c+2)*EOUT + o];
      float w3 = R[O_A + (which*FOUT + c+3)*EOUT + o];
      #pragma unroll
      for (int r = 0; r < 4; ++r){
        float4 h4 = *(const float4*)&hrow[(hh*4+r)*FOUT + c];
        a4[r] += h4.x*w0 + h4.y*w1 + h4.z*w2 + h4.w*w3;
      }
    }
    int ob = which ? O_Q : O_P;
    #pragma unroll
    for (int r = 0; r < 4; ++r)
      Wr[ob + (b*N + i0 + hh*4 + r)*EOUT + o] = a4[r];
  }
}

// K2: su/sv scalars
__global__ __launch_bounds__(64) void k_susv(const float* __restrict__ R, float* __restrict__ Wr){
  int blk = blockIdx.x; int b = blk >> 7, r = blk & 127; int o = threadIdx.x;
  float fw = R[O_FCW + o];
  float u = R[O_P + (b*N + r)*EOUT + o] + R[O_Q + (b*N + r)*EOUT + o];
  float t1 = lrelu(u) * fw;
  int j2 = (2*r) & 127;
  float v = R[O_P + (b*N + j2)*EOUT + o] + R[O_Q + (b*N + j2 + 1)*EOUT + o];
  float t2 = lrelu(v) * fw;
  for (int off = 32; off; off >>= 1){ t1 += __shfl_down(t1, off); t2 += __shfl_down(t2, off); }
  if (o == 0){ Wr[O_SU + b*N + r] = t1; Wr[O_SV + b*N + r] = t2; }
}

// K3: per (b,i): edge-MLP + mask + softmax -> att (stored) ; hn_pre ; z (RNN input)
__global__ __launch_bounds__(128) void k_att(const int* __restrict__ adj,
                                             const float* __restrict__ R,
                                             float* __restrict__ Wr){
  int blk = blockIdx.x; int b = blk >> 7, i = blk & 127; int tid = threadIdx.x;
  __shared__ __align__(16) float wel[N*BINW];
  __shared__ __align__(16) float attl[N];
  __shared__ __align__(16) float hnp[N];
  __shared__ float red2[2];
  int base_we = (b*N + i)*N*BINW;
  for (int t4 = tid; t4 < N*BINW/4; t4 += 128)
    *(float4*)&wel[t4*4] = *(const float4*)&R[O_WE + base_we + t4*4];
  __syncthreads();
  int j = tid;
  float wr[BINW];
  #pragma unroll
  for (int t = 0; t < BINW; ++t) wr[t] = wel[j*BINW + t];
  float wcon = 0.f;
  for (int o = 0; o < BOUT; ++o){
    float wp = R[O_WFCB + o];                 // uniform addresses -> scalarizable
    #pragma unroll
    for (int t = 0; t < BINW; ++t) wp += wr[t] * R[O_WFCW + t*BOUT + o];
    wcon += lrelu(wp) * R[O_FCW + EOUT + o];
  }
  float econ = (i < 64) ? R[O_SU + b*N + 2*i + (j >= 64 ? 1 : 0)]
                        : R[O_SV + b*N + j];
  float etot = econ + wcon + R[O_FCB];
  float m = (adj[(b*N + i)*N + j] > 0) ? etot : -9e15f;
  float mx = m;
  for (int off = 32; off; off >>= 1) mx = fmaxf(mx, __shfl_xor(mx, off));
  if ((tid & 63) == 0) red2[tid >> 6] = mx;
  __syncthreads();
  mx = fmaxf(red2[0], red2[1]);
  float ev = expf(m - mx);
  float sum = ev;
  for (int off = 32; off; off >>= 1) sum += __shfl_xor(sum, off);
  __syncthreads();
  if ((tid & 63) == 0) red2[tid >> 6] = sum;
  __syncthreads();
  sum = red2[0] + red2[1];
  float att = ev / sum;
  attl[j] = att;
  Wr[O_ATT + (b*N + i)*N + j] = att;
  float sbi = R[O_S + b*N + i];
  hnp[j] = lrelu(att * sbi + R[O_FCCB]);
  __syncthreads();
  // z[b,i,c] both directions
  {
    int d = tid >> 6, c = tid & 63;
    int wb = d ? O_WIHB : O_WIHF;
    float acc = R[(d ? O_BIHB : O_BIHF) + c] + R[(d ? O_BHHB : O_BHHF) + c];
    #pragma unroll 8
    for (int k = 0; k < N; k += 4){
      float4 h4 = *(const float4*)&hnp[k];
      float4 w4 = *(const float4*)&R[wb + c*N + k];
      acc += h4.x*w4.x + h4.y*w4.y + h4.z*w4.z + h4.w*w4.w;
    }
    Wr[(d ? O_ZB : O_ZF) + (b*N + i)*CI + c] = acc;
  }
}

// K4: recurrence — one wave per (dir,batch); h in registers, readlane broadcast
__global__ __launch_bounds__(64) void k_rnn(float* __restrict__ ws){
  int blk = blockIdx.x; int d = blk >> 4, b = blk & 15; int c = threadIdx.x;
  const int wb = d ? O_WHHB : O_WHHF;
  const int zb = d ? O_ZB : O_ZF;
  const int ob = d ? O_RB : O_RF;
  float wreg[CI];
  #pragma unroll
  for (int k = 0; k < CI; k += 4){
    float4 w4 = *(const float4*)&ws[wb + c*CI + k];
    wreg[k]=w4.x; wreg[k+1]=w4.y; wreg[k+2]=w4.z; wreg[k+3]=w4.w;
  }
  const int step = d ? -1 : 1;
  int tt = d ? (N-1) : 0;
  float hv = 0.f;
  float znext = ws[zb + (b*N + tt)*CI + c];
  for (int t = 0; t < N; ++t){
    float z = znext;
    if (t < N-1) znext = ws[zb + (b*N + tt + step)*CI + c];
    float a0 = z, a1 = 0.f, a2 = 0.f, a3 = 0.f;
    #pragma unroll
    for (int k = 0; k < CI; k += 4){
      a0 = fmaf(bcastf(hv, k+0), wreg[k+0], a0);
      a1 = fmaf(bcastf(hv, k+1), wreg[k+1], a1);
      a2 = fmaf(bcastf(hv, k+2), wreg[k+2], a2);
      a3 = fmaf(bcastf(hv, k+3), wreg[k+3], a3);
    }
    float x = (a0+a1)+(a2+a3);
    x = fminf(15.f, fmaxf(-15.f, x));
    float p = __expf(2.f * x);
    hv = __fdividef(p - 1.f, p + 1.f);
    ws[ob + (b*N + tt)*CI + c] = hv;
    tt += step;
  }
}

// K5: h1 = att @ h, 8 rows per block for h-tile reuse
__global__ __launch_bounds__(256) void k_h1(const float* __restrict__ R, float* __restrict__ Wr){
  int b = blockIdx.x >> 4, i0 = (blockIdx.x & 15) * 8;
  int f = threadIdx.x;
  __shared__ __align__(16) float attT[N*8];   // [k][r]
  for (int t = threadIdx.x; t < 8*N; t += 256){
    int r = t >> 7, k = t & 127;
    attT[k*8 + r] = R[O_ATT + (b*N + i0 + r)*N + k];
  }
  __syncthreads();
  float acc[8] = {0,0,0,0,0,0,0,0};
  for (int k = 0; k < N; ++k){
    float hv = R[O_H + (b*N + k)*FOUT + f];
    float4 a0 = *(const float4*)&attT[k*8];
    float4 a1 = *(const float4*)&attT[k*8 + 4];
    acc[0] += a0.x*hv; acc[1] += a0.y*hv; acc[2] += a0.z*hv; acc[3] += a0.w*hv;
    acc[4] += a1.x*hv; acc[5] += a1.y*hv; acc[6] += a1.z*hv; acc[7] += a1.w*hv;
  }
  #pragma unroll
  for (int r = 0; r < 8; ++r)
    Wr[O_H1 + (b*N + i0 + r)*FOUT + f] = acc[r];
}

// K6: out = elu(cat(lrelu(rnn_f), lrelu(rnn_b), h1) @ fco_w + fco_b)
__global__ __launch_bounds__(256) void k_out(const void* __restrict__ x0,
                                             const float* __restrict__ R, void* dout){
  int blk = blockIdx.x, tid = threadIdx.x;
  int b = blk >> 5, i0 = (blk & 31) * 4;
  constexpr int KW = 2*CI + FOUT;  // 416
  __shared__ __align__(16) float inl[4*KW];
  __shared__ int smode;
  if (tid == 0) smode = detect_bf16(x0);
  for (int t = tid; t < 4*KW; t += 256){
    int r = t / KW, k = t % KW;
    int row = b*N + i0 + r;
    float v;
    if (k < CI)        v = lrelu(R[O_RF + row*CI + k]);
    else if (k < 2*CI) v = lrelu(R[O_RB + row*CI + (k - CI)]);
    else               v = R[O_H1 + row*FOUT + (k - 2*CI)];
    inl[t] = v;
  }
  __syncthreads();
  int l = tid;
  float bias = R[O_FCOB + l];
  float acc[4] = {bias, bias, bias, bias};
  for (int k = 0; k < KW; k += 4){
    float w0 = R[O_FCOW + (k+0)*L1 + l];
    float w1 = R[O_FCOW + (k+1)*L1 + l];
    float w2 = R[O_FCOW + (k+2)*L1 + l];
    float w3 = R[O_FCOW + (k+3)*L1 + l];
    #pragma unroll
    for (int r = 0; r < 4; ++r){
      float4 v = *(const float4*)&inl[r*KW + k];
      acc[r] += v.x*w0 + v.y*w1 + v.z*w2 + v.w*w3;
    }
  }
  int mode = smode;
  #pragma unroll
  for (int r = 0; r < 4; ++r){
    float o = acc[r] > 0.f ? acc[r] : expm1f(acc[r]);
    int idx = (b*N + i0 + r)*L1 + l;
    if (mode) ((__hip_bfloat16*)dout)[idx] = __float2bfloat16(o);
    else      ((float*)dout)[idx] = o;
  }
}

extern "C" void kernel_launch(void* const* d_in, const int* in_sizes, int n_in,
                              void* d_out, int out_size, void* d_ws, size_t ws_size,
                              hipStream_t stream){
  (void)in_sizes; (void)n_in; (void)out_size; (void)ws_size;
  float* ws = (float*)d_ws;
  ConvArgs ca;
  const int map[NCONV] = {0,2,3,4,5,6,7,8,9,10,11,12,13,14,15,16,17,18,19,20};
  for (int t = 0; t < NCONV; ++t) ca.p[t] = d_in[map[t]];
  hipLaunchKernelGGL(k_convert, dim3(2048), dim3(256), 0, stream, ca, ws);
  hipLaunchKernelGGL(k_h_pq,   dim3(256),  dim3(256), 0, stream, ws, ws);
  hipLaunchKernelGGL(k_susv,   dim3(B*N),  dim3(64),  0, stream, ws, ws);
  hipLaunchKernelGGL(k_att,    dim3(B*N),  dim3(128), 0, stream, (const int*)d_in[1], ws, ws);
  hipLaunchKernelGGL(k_rnn,    dim3(32),   dim3(64),  0, stream, ws);
  hipLaunchKernelGGL(k_h1,     dim3(256),  dim3(256), 0, stream, ws, ws);
  hipLaunchKernelGGL(k_out,    dim3(B*N/4), dim3(256), 0, stream, d_in[0], ws, d_out);
}